// Round 1
// baseline (103.007 us; speedup 1.0000x reference)
//
#include <hip/hip_runtime.h>
#include <math.h>

#define H 256
#define W 256
#define BATCH 16
#define XT 16                      // columns per block in the EDT kernel

__device__ __constant__ float kBIG = 1.0e6f;

// ---------------------------------------------------------------------------
// Kernel 1: one block per (image b, row y).
//  - binarize target, compute target_edge for this row (needs rows y-1..y+1)
//  - 1D row distance to nearest edge via prefix/suffix min-plus scans
//  - store g^2 into ws  (g clamped at 1e6 like the reference)
// ---------------------------------------------------------------------------
__global__ __launch_bounds__(256) void k_rowdist(const float* __restrict__ target,
                                                 float* __restrict__ g2out) {
    const int y = blockIdx.x;
    const int b = blockIdx.y;
    const int x = threadIdx.x;
    const float* timg = target + (size_t)b * H * W;

    __shared__ int   nt[3][W + 2];   // "hole" flags (!target), col-padded with 0
    __shared__ float A[W], Bv[W];    // scan arrays

    if (x < 3) { nt[x][0] = 0; nt[x][W + 1] = 0; }
    // rows y-1, y, y+1; out-of-image rows contribute no holes (maxpool pad=-inf)
    nt[0][x + 1] = (y > 0)     ? ((timg[(y - 1) * W + x] > 0.5f) ? 0 : 1) : 0;
    nt[1][x + 1] =               ((timg[ y      * W + x] > 0.5f) ? 0 : 1);
    nt[2][x + 1] = (y < H - 1) ? ((timg[(y + 1) * W + x] > 0.5f) ? 0 : 1) : 0;
    __syncthreads();

    int holes = 0;
    #pragma unroll
    for (int r = 0; r < 3; ++r)
        holes |= nt[r][x] | nt[r][x + 1] | nt[r][x + 2];
    const int edge = (nt[1][x + 1] == 0) && holes;   // target && has off-neighbor

    const float f = edge ? 0.0f : 1.0e6f;
    A[x]  = f - (float)x;    // prefix-min of (f[k]-k)  -> dfwd = x + pmin
    Bv[x] = f + (float)x;    // suffix-min of (f[k]+k)  -> dbwd = smin - x
    __syncthreads();

    #pragma unroll
    for (int off = 1; off < W; off <<= 1) {
        float va = (x >= off)    ? A[x - off]   : 3.0e38f;
        float vb = (x + off < W) ? Bv[x + off]  : 3.0e38f;
        __syncthreads();
        A[x]  = fminf(A[x],  va);
        Bv[x] = fminf(Bv[x], vb);
        __syncthreads();
    }

    float g = fminf((float)x + A[x], Bv[x] - (float)x);
    g = fminf(g, 1.0e6f);                       // reference clamps at BIG
    g2out[((size_t)b * H + y) * W + x] = g * g;
}

// ---------------------------------------------------------------------------
// Kernel 2: one block per (image b, 16-column tile).
//  - stage g2[:,tile] (16KB) and haloed binarized pred tile in LDS
//  - each thread: 16 output pixels (same column), min over 256 y' in VGPRs
//  - pred_edge on the fly, block reduction, atomic add of pre-scaled partial
// ---------------------------------------------------------------------------
__global__ __launch_bounds__(256) void k_edt(const float* __restrict__ g2,
                                             const float* __restrict__ pred,
                                             float* __restrict__ out) {
    const int b  = blockIdx.y;
    const int x0 = blockIdx.x * XT;
    const int t  = threadIdx.x;

    __shared__ float         g2s[H][XT];              // 16 KB
    __shared__ unsigned char ph[H + 2][XT + 2];       // pred hole flags, padded 0
    __shared__ float         red[256];

    const float* gimg = g2   + (size_t)b * H * W;
    const float* pimg = pred + (size_t)b * H * W;

    #pragma unroll
    for (int i = 0; i < (H * XT) / 256; ++i) {
        int idx = t + i * 256;
        int yy = idx / XT, xx = idx % XT;
        g2s[yy][xx] = gimg[yy * W + x0 + xx];
    }
    for (int idx = t; idx < (H + 2) * (XT + 2); idx += 256) {
        int yy = idx / (XT + 2);          // padded row
        int xx = idx % (XT + 2);          // padded col
        int gy = yy - 1, gx = x0 + xx - 1;
        unsigned char v = 0;              // out-of-bounds: not a hole
        if (gy >= 0 && gy < H && gx >= 0 && gx < W)
            v = (pimg[gy * W + gx] > 0.5f) ? 0 : 1;
        ph[yy][xx] = v;
    }
    __syncthreads();

    const int xl = t & (XT - 1);
    const int yb = t >> 4;                // 0..15
    float yv[16], m[16];
    #pragma unroll
    for (int j = 0; j < 16; ++j) { yv[j] = (float)(yb + 16 * j); m[j] = 3.0e38f; }

    for (int yp = 0; yp < H; ++yp) {
        float gv  = g2s[yp][xl];          // broadcast across lanes: conflict-free
        float fyp = (float)yp;
        #pragma unroll
        for (int j = 0; j < 16; ++j) {
            float dy = yv[j] - fyp;
            m[j] = fminf(m[j], fmaf(dy, dy, gv));
        }
    }

    float local = 0.0f;
    #pragma unroll
    for (int j = 0; j < 16; ++j) {
        int y = yb + 16 * j;
        int holes = 0;
        #pragma unroll
        for (int r = 0; r < 3; ++r)
            holes |= ph[y + r][xl] | ph[y + r][xl + 1] | ph[y + r][xl + 2];
        int edge = (ph[y + 1][xl + 1] == 0) && holes;   // pred && has off-neighbor
        if (edge) local += sqrtf(m[j]);
    }

    red[t] = local;
    __syncthreads();
    #pragma unroll
    for (int s = 128; s > 0; s >>= 1) {
        if (t < s) red[t] += red[t + s];
        __syncthreads();
    }
    if (t == 0)
        atomicAdd(out, red[0] * (1.0f / ((float)BATCH * H * W)));
}

// ---------------------------------------------------------------------------
extern "C" void kernel_launch(void* const* d_in, const int* in_sizes, int n_in,
                              void* d_out, int out_size, void* d_ws, size_t ws_size,
                              hipStream_t stream) {
    const float* pred   = (const float*)d_in[0];
    const float* target = (const float*)d_in[1];
    float* out = (float*)d_out;
    float* g2  = (float*)d_ws;            // needs B*H*W*4 = 4 MB of workspace

    hipMemsetAsync(d_out, 0, sizeof(float), stream);   // out is atomic-accumulated

    dim3 grid1(H, BATCH);
    k_rowdist<<<grid1, 256, 0, stream>>>(target, g2);

    dim3 grid2(W / XT, BATCH);
    k_edt<<<grid2, 256, 0, stream>>>(g2, pred, out);
}

// Round 2
// 89.822 us; speedup vs baseline: 1.1468x; 1.1468x over previous
//
#include <hip/hip_runtime.h>
#include <math.h>

#define H 256
#define W 256
#define BATCH 16
#define XT 16      // columns per k_edt block
#define YT 64      // output rows per k_edt block

// ---------------------------------------------------------------------------
// Kernel 1: one block per (image b, row y).
//  - binarize target, compute target_edge for this row (rows y-1..y+1)
//  - 1D row distance via wave-level min-plus shuffle scans (2 barriers total)
//  - store g^2 into ws; block (0,0) thread 0 also zeroes the output scalar
// ---------------------------------------------------------------------------
__global__ __launch_bounds__(256) void k_rowdist(const float* __restrict__ target,
                                                 float* __restrict__ g2out,
                                                 float* __restrict__ out) {
    const int y = blockIdx.x;
    const int b = blockIdx.y;
    const int x = threadIdx.x;

    if (b == 0 && y == 0 && x == 0) out[0] = 0.0f;  // k_edt atomics run after us

    const float* timg = target + (size_t)b * H * W;

    __shared__ int   nt[3][W + 2];   // "hole" flags (!target), col-padded with 0
    __shared__ float wtotA[4], wtotB[4];

    if (x < 3) { nt[x][0] = 0; nt[x][W + 1] = 0; }
    nt[0][x + 1] = (y > 0)     ? ((timg[(y - 1) * W + x] > 0.5f) ? 0 : 1) : 0;
    nt[1][x + 1] =               ((timg[ y      * W + x] > 0.5f) ? 0 : 1);
    nt[2][x + 1] = (y < H - 1) ? ((timg[(y + 1) * W + x] > 0.5f) ? 0 : 1) : 0;
    __syncthreads();

    int holes = 0;
    #pragma unroll
    for (int r = 0; r < 3; ++r)
        holes |= nt[r][x] | nt[r][x + 1] | nt[r][x + 2];
    const int edge = (nt[1][x + 1] == 0) && holes;

    const float f = edge ? 0.0f : 1.0e6f;
    float A  = f - (float)x;    // prefix-min of (f[k]-k)  -> dfwd = x + pmin
    float Bv = f + (float)x;    // suffix-min of (f[k]+k)  -> dbwd = smin - x

    const int lane = x & 63;
    const int wv   = x >> 6;

    #pragma unroll
    for (int off = 1; off < 64; off <<= 1) {
        float va = __shfl_up(A, off, 64);
        if (lane >= off) A = fminf(A, va);
        float vb = __shfl_down(Bv, off, 64);
        if (lane < 64 - off) Bv = fminf(Bv, vb);
    }
    if (lane == 63) wtotA[wv] = A;    // wave-inclusive prefix total
    if (lane == 0)  wtotB[wv] = Bv;   // wave-inclusive suffix total
    __syncthreads();
    #pragma unroll
    for (int w2 = 0; w2 < 4; ++w2) {
        if (w2 < wv) A  = fminf(A,  wtotA[w2]);
        if (w2 > wv) Bv = fminf(Bv, wtotB[w2]);
    }

    float g = fminf((float)x + A, Bv - (float)x);
    g = fminf(g, 1.0e6f);                       // reference clamps at BIG
    g2out[((size_t)b * H + y) * W + x] = g * g;
}

// ---------------------------------------------------------------------------
// Kernel 2: one block per (image b, 64-row x 16-col output tile) = 1024 blocks
//  (4 blocks/CU -> 4 waves/SIMD: latency actually hidden, unlike 1 block/CU).
//  - stage g2[:,tile] (16KB, all 256 y') + haloed binarized pred tile in LDS
//  - each thread: 4 output pixels (same column), min over 256 y' in VGPRs,
//    y' unrolled x4 so 4 LDS broadcasts are in flight
//  - pred_edge on the fly, shuffle reduction, one atomic per block
// ---------------------------------------------------------------------------
__global__ __launch_bounds__(256) void k_edt(const float* __restrict__ g2,
                                             const float* __restrict__ pred,
                                             float* __restrict__ out) {
    const int b  = blockIdx.z;
    const int y0 = blockIdx.y * YT;
    const int x0 = blockIdx.x * XT;
    const int t  = threadIdx.x;

    __shared__ float         g2s[H][XT];              // 16 KB, full column strip
    __shared__ unsigned char ph[YT + 2][XT + 2];      // pred hole flags, halo'd
    __shared__ float         red[4];

    const float* gimg = g2   + (size_t)b * H * W;
    const float* pimg = pred + (size_t)b * H * W;

    #pragma unroll
    for (int i = 0; i < (H * XT) / 256; ++i) {        // 16 coalesced iters
        int idx = t + i * 256;
        int yy = idx >> 4, xx = idx & 15;
        g2s[yy][xx] = gimg[yy * W + x0 + xx];
    }
    for (int idx = t; idx < (YT + 2) * (XT + 2); idx += 256) {
        int yy = idx / (XT + 2);
        int xx = idx % (XT + 2);
        int gy = y0 + yy - 1, gx = x0 + xx - 1;
        unsigned char v = 0;              // out-of-bounds: not a hole
        if (gy >= 0 && gy < H && gx >= 0 && gx < W)
            v = (pimg[gy * W + gx] > 0.5f) ? 0 : 1;
        ph[yy][xx] = v;
    }
    __syncthreads();

    const int xl = t & (XT - 1);
    const int yb = t >> 4;                // 0..15
    float yv[4], m[4];
    #pragma unroll
    for (int j = 0; j < 4; ++j) {
        yv[j] = (float)(y0 + yb + 16 * j);
        m[j]  = 3.0e38f;
    }

    for (int yp = 0; yp < H; yp += 4) {
        #pragma unroll
        for (int u = 0; u < 4; ++u) {
            float gv  = g2s[yp + u][xl];  // broadcast across lanes: conflict-free
            float fyp = (float)(yp + u);
            #pragma unroll
            for (int j = 0; j < 4; ++j) {
                float dy = yv[j] - fyp;
                m[j] = fminf(m[j], fmaf(dy, dy, gv));
            }
        }
    }

    float local = 0.0f;
    #pragma unroll
    for (int j = 0; j < 4; ++j) {
        int yy = yb + 16 * j;             // local output row in [0,YT)
        int holes = 0;
        #pragma unroll
        for (int r = 0; r < 3; ++r)
            holes |= ph[yy + r][xl] | ph[yy + r][xl + 1] | ph[yy + r][xl + 2];
        int edge = (ph[yy + 1][xl + 1] == 0) && holes;
        if (edge) local += sqrtf(m[j]);
    }

    // wave shuffle reduction, then 4 partials through LDS
    #pragma unroll
    for (int off = 32; off > 0; off >>= 1)
        local += __shfl_down(local, off, 64);
    if ((t & 63) == 0) red[t >> 6] = local;
    __syncthreads();
    if (t == 0)
        atomicAdd(out, (red[0] + red[1] + red[2] + red[3]) *
                           (1.0f / ((float)BATCH * H * W)));
}

// ---------------------------------------------------------------------------
extern "C" void kernel_launch(void* const* d_in, const int* in_sizes, int n_in,
                              void* d_out, int out_size, void* d_ws, size_t ws_size,
                              hipStream_t stream) {
    const float* pred   = (const float*)d_in[0];
    const float* target = (const float*)d_in[1];
    float* out = (float*)d_out;
    float* g2  = (float*)d_ws;            // needs B*H*W*4 = 4 MB of workspace

    dim3 grid1(H, BATCH);
    k_rowdist<<<grid1, 256, 0, stream>>>(target, g2, out);

    dim3 grid2(W / XT, H / YT, BATCH);
    k_edt<<<grid2, 256, 0, stream>>>(g2, pred, out);
}

// Round 3
// 86.703 us; speedup vs baseline: 1.1880x; 1.0360x over previous
//
#include <hip/hip_runtime.h>
#include <math.h>

#define H 256
#define W 256
#define BATCH 16
#define XT 16         // columns per k_edt block
#define YT 64         // output rows per k_edt block
#define GS (H + 4)    // transposed g2 LDS row stride: 260 floats -> 16B-aligned
                      // rows, b128 start banks 4*xl -> exact 2-way (free, m136)

typedef float vf2 __attribute__((ext_vector_type(2)));
typedef float vf4 __attribute__((ext_vector_type(4)));

// ---------------------------------------------------------------------------
// Kernel 1: one block per (image b, row y).
//  - binarize target, compute target_edge for this row (rows y-1..y+1)
//  - 1D row distance via wave-level min-plus shuffle scans (2 barriers total)
//  - store g^2 into ws; block (0,0) thread 0 also zeroes the output scalar
// ---------------------------------------------------------------------------
__global__ __launch_bounds__(256) void k_rowdist(const float* __restrict__ target,
                                                 float* __restrict__ g2out,
                                                 float* __restrict__ out) {
    const int y = blockIdx.x;
    const int b = blockIdx.y;
    const int x = threadIdx.x;

    if (b == 0 && y == 0 && x == 0) out[0] = 0.0f;  // k_edt atomics run after us

    const float* timg = target + (size_t)b * H * W;

    __shared__ int   nt[3][W + 2];   // "hole" flags (!target), col-padded with 0
    __shared__ float wtotA[4], wtotB[4];

    if (x < 3) { nt[x][0] = 0; nt[x][W + 1] = 0; }
    nt[0][x + 1] = (y > 0)     ? ((timg[(y - 1) * W + x] > 0.5f) ? 0 : 1) : 0;
    nt[1][x + 1] =               ((timg[ y      * W + x] > 0.5f) ? 0 : 1);
    nt[2][x + 1] = (y < H - 1) ? ((timg[(y + 1) * W + x] > 0.5f) ? 0 : 1) : 0;
    __syncthreads();

    int holes = 0;
    #pragma unroll
    for (int r = 0; r < 3; ++r)
        holes |= nt[r][x] | nt[r][x + 1] | nt[r][x + 2];
    const int edge = (nt[1][x + 1] == 0) && holes;

    const float f = edge ? 0.0f : 1.0e6f;
    float A  = f - (float)x;    // prefix-min of (f[k]-k)  -> dfwd = x + pmin
    float Bv = f + (float)x;    // suffix-min of (f[k]+k)  -> dbwd = smin - x

    const int lane = x & 63;
    const int wv   = x >> 6;

    #pragma unroll
    for (int off = 1; off < 64; off <<= 1) {
        float va = __shfl_up(A, off, 64);
        if (lane >= off) A = fminf(A, va);
        float vb = __shfl_down(Bv, off, 64);
        if (lane < 64 - off) Bv = fminf(Bv, vb);
    }
    if (lane == 63) wtotA[wv] = A;    // wave-inclusive prefix total
    if (lane == 0)  wtotB[wv] = Bv;   // wave-inclusive suffix total
    __syncthreads();
    #pragma unroll
    for (int w2 = 0; w2 < 4; ++w2) {
        if (w2 < wv) A  = fminf(A,  wtotA[w2]);
        if (w2 > wv) Bv = fminf(Bv, wtotB[w2]);
    }

    float g = fminf((float)x + A, Bv - (float)x);
    g = fminf(g, 1.0e6f);                       // reference clamps at BIG
    g2out[((size_t)b * H + y) * W + x] = g * g;
}

// ---------------------------------------------------------------------------
// Kernel 2: one block per (image b, 64-row x 16-col output tile) = 1024 blocks
//  (4 blocks/CU, 4 waves/SIMD). g2 strip staged TRANSPOSED in LDS so 4
//  consecutive y' are one ds_read_b128; inner math in packed fp32
//  (v_pk_add/v_pk_fma) + v_min3 -> 6 instrs per output per 4 y'.
// ---------------------------------------------------------------------------
__global__ __launch_bounds__(256) void k_edt(const float* __restrict__ g2,
                                             const float* __restrict__ pred,
                                             float* __restrict__ out) {
    const int b  = blockIdx.z;
    const int y0 = blockIdx.y * YT;
    const int x0 = blockIdx.x * XT;
    const int t  = threadIdx.x;

    __shared__ float         g2s[XT][GS];             // 16.6 KB, transposed strip
    __shared__ unsigned char ph[YT + 2][XT + 2];      // pred hole flags, halo'd
    __shared__ float         red[4];

    const float* gimg = g2   + (size_t)b * H * W;
    const float* pimg = pred + (size_t)b * H * W;

    #pragma unroll
    for (int i = 0; i < (H * XT) / 256; ++i) {        // 16 coalesced-ish iters
        int idx = t + i * 256;
        int yy = idx >> 4, xx = idx & 15;
        g2s[xx][yy] = gimg[yy * W + x0 + xx];         // transpose on store
    }
    for (int idx = t; idx < (YT + 2) * (XT + 2); idx += 256) {
        int yy = idx / (XT + 2);
        int xx = idx % (XT + 2);
        int gy = y0 + yy - 1, gx = x0 + xx - 1;
        unsigned char v = 0;              // out-of-bounds: not a hole
        if (gy >= 0 && gy < H && gx >= 0 && gx < W)
            v = (pimg[gy * W + gx] > 0.5f) ? 0 : 1;
        ph[yy][xx] = v;
    }
    __syncthreads();

    const int xl = t & (XT - 1);
    const int yb = t >> 4;                // 0..15
    float yvf[4];
    vf2   m2[4];
    #pragma unroll
    for (int j = 0; j < 4; ++j) {
        yvf[j] = (float)(y0 + yb + 16 * j);
        m2[j]  = (vf2){3.0e38f, 3.0e38f};
    }

    vf2 p0 = (vf2){0.0f, 1.0f};
    vf2 p1 = (vf2){2.0f, 3.0f};
    const vf2 four = (vf2){4.0f, 4.0f};
    const float* grow = &g2s[xl][0];

    for (int yp = 0; yp < H; yp += 4) {
        vf4 g4 = *(const vf4*)(grow + yp);            // one ds_read_b128
        vf2 ga = (vf2){g4.x, g4.y};
        vf2 gb = (vf2){g4.z, g4.w};
        #pragma unroll
        for (int j = 0; j < 4; ++j) {
            vf2 yj  = (vf2){yvf[j], yvf[j]};
            vf2 dy0 = yj - p0;                        // v_pk_add_f32
            vf2 dy1 = yj - p1;
            vf2 d0  = dy0 * dy0 + ga;                 // v_pk_fma_f32
            vf2 d1  = dy1 * dy1 + gb;
            m2[j].x = fminf(fminf(m2[j].x, d0.x), d1.x);   // v_min3_f32
            m2[j].y = fminf(fminf(m2[j].y, d0.y), d1.y);
        }
        p0 += four;
        p1 += four;
    }

    float local = 0.0f;
    #pragma unroll
    for (int j = 0; j < 4; ++j) {
        float mj = fminf(m2[j].x, m2[j].y);
        int yy = yb + 16 * j;             // local output row in [0,YT)
        int holes = 0;
        #pragma unroll
        for (int r = 0; r < 3; ++r)
            holes |= ph[yy + r][xl] | ph[yy + r][xl + 1] | ph[yy + r][xl + 2];
        int edge = (ph[yy + 1][xl + 1] == 0) && holes;
        if (edge) local += sqrtf(mj);
    }

    // wave shuffle reduction, then 4 partials through LDS
    #pragma unroll
    for (int off = 32; off > 0; off >>= 1)
        local += __shfl_down(local, off, 64);
    if ((t & 63) == 0) red[t >> 6] = local;
    __syncthreads();
    if (t == 0)
        atomicAdd(out, (red[0] + red[1] + red[2] + red[3]) *
                           (1.0f / ((float)BATCH * H * W)));
}

// ---------------------------------------------------------------------------
extern "C" void kernel_launch(void* const* d_in, const int* in_sizes, int n_in,
                              void* d_out, int out_size, void* d_ws, size_t ws_size,
                              hipStream_t stream) {
    const float* pred   = (const float*)d_in[0];
    const float* target = (const float*)d_in[1];
    float* out = (float*)d_out;
    float* g2  = (float*)d_ws;            // needs B*H*W*4 = 4 MB of workspace

    dim3 grid1(H, BATCH);
    k_rowdist<<<grid1, 256, 0, stream>>>(target, g2, out);

    dim3 grid2(W / XT, H / YT, BATCH);
    k_edt<<<grid2, 256, 0, stream>>>(g2, pred, out);
}